// Round 3
// baseline (697.442 us; speedup 1.0000x reference)
//
#include <hip/hip_runtime.h>

#define NN 8000
#define NPP 1000
#define FF 1000
#define HCC 32
#define KK 5
#define EE 80000
#define TRIN 499500
#define HID 128
#define EPSV 1e-5f
#define NREP 64

// workspace layout (4-byte units)
#define IDX_ACC  0          // NREP x 1024 fp32 (zeroed by memset)
#define IDX_ROWS 65536      // 8001 ints
#define IDX_EPAK 73600      // 80000 int2 (src local id, weight bits)
#define IDX_H1   233600     // 8000*32 fp32
#define IDX_H2   489600     // 8000*32 fp32
#define IDX_EMB  745600     // 768 fp32 (direct stores, no init needed)

// ---------------- fused graph preprocessing (one workgroup) ----------------
// count(dst) -> scan -> rows; count(src) -> deg; fill CSR as int2{src%NPP, w}
__global__ void __launch_bounds__(1024) k_prep(const int* __restrict__ src,
                                               const int* __restrict__ dst,
                                               int* __restrict__ rows_g,
                                               int2* __restrict__ epak) {
  __shared__ int arrA[8000];
  __shared__ int arrB[8000];
  const int t = threadIdx.x;
  // phase 1: count dst into arrA
  for (int i = t; i < NN; i += 1024) arrA[i] = 0;
  __syncthreads();
  for (int e = t; e < EE; e += 1024) atomicAdd(&arrA[dst[e]], 1);
  __syncthreads();
  // phase 2: exclusive scan of arrA -> row starts (ssum in arrB[0..1023])
  int loc[8];
  int s = 0;
  const int base = t * 8;
#pragma unroll
  for (int q = 0; q < 8; ++q) {
    int idx = base + q;
    int v = (idx < NN) ? arrA[idx] : 0;
    loc[q] = s;
    s += v;
  }
  __syncthreads();
  arrB[t] = s;
  __syncthreads();
  for (int d = 1; d < 1024; d <<= 1) {
    int v = (t >= d) ? arrB[t - d] : 0;
    __syncthreads();
    arrB[t] += v;
    __syncthreads();
  }
  int off = (t == 0) ? 0 : arrB[t - 1];
  int rstart[8];
#pragma unroll
  for (int q = 0; q < 8; ++q) {
    int idx = base + q;
    rstart[q] = off + loc[q];
    if (idx < NN) rows_g[idx] = rstart[q];
  }
  if (t == 0) rows_g[NN] = EE;
  __syncthreads();  // everyone done reading ssum before repurposing arrB
  // arrB becomes running fill cursor initialized at row start
#pragma unroll
  for (int q = 0; q < 8; ++q) {
    int idx = base + q;
    if (idx < NN) arrB[idx] = rstart[q];
  }
  // phase 3: arrA becomes src-degree
  __syncthreads();
  for (int i = t; i < NN; i += 1024) arrA[i] = 0;
  __syncthreads();
  for (int e = t; e < EE; e += 1024) atomicAdd(&arrA[src[e]], 1);
  __syncthreads();
  // phase 4: fill
  for (int e = t; e < EE; e += 1024) {
    int s0 = src[e], d0 = dst[e];
    int p = atomicAdd(&arrB[d0], 1);
    int dd = arrA[d0];
    float w = -rsqrtf((float)arrA[s0]) * ((dd > 0) ? rsqrtf((float)dd) : 0.0f);
    int2 pk;
    pk.x = s0 % NPP;
    pk.y = __float_as_int(w);
    epak[p] = pk;
  }
}

// ---------------- fused Chebyshev layer (Clenshaw, LDS-resident) ----------------
// one workgroup per (graph g, column c); 1024 threads, thread t owns row t.
// hin == null  -> layer-0: ck[k][i] = cw[k][i][c]   (identity input, tiled)
// hin != null  -> ck[k][i] = sum_j hin[g,i,j] * cw[k][j][c]
// 4 Clenshaw steps entirely in LDS; h -> hout (if any) + column mean -> emb.
__global__ void __launch_bounds__(1024, 4) k_layer(
    const float* __restrict__ cw, const float* __restrict__ bias,
    const float* __restrict__ hin, float* __restrict__ hout,
    const int* __restrict__ rows, const int2* __restrict__ epak,
    float* __restrict__ emb, int L) {
  __shared__ float ckl[KK][NPP];
  __shared__ float bcur[NPP];
  __shared__ float wcol[KK][HCC];
  __shared__ float part[32];
  const int t = threadIdx.x;
  const int g = blockIdx.x >> 5;
  const int c = blockIdx.x & 31;
  const bool act = t < NPP;
  // build coefficient columns
  if (hin == nullptr) {
    if (act) {
#pragma unroll
      for (int k = 0; k < KK; ++k)
        ckl[k][t] = cw[k * (FF * HCC) + t * HCC + c];
    }
  } else {
    if (t < KK * HCC) {
      int k = t >> 5, j = t & 31;
      wcol[k][j] = cw[k * (HCC * HCC) + j * HCC + c];
    }
    __syncthreads();
    if (act) {
      float hrow[HCC];
      const float* hp = hin + ((size_t)g * NPP + t) * HCC;
#pragma unroll
      for (int q = 0; q < HCC / 4; ++q) {
        float4 f = *(const float4*)(hp + q * 4);
        hrow[q * 4 + 0] = f.x; hrow[q * 4 + 1] = f.y;
        hrow[q * 4 + 2] = f.z; hrow[q * 4 + 3] = f.w;
      }
#pragma unroll
      for (int k = 0; k < KK; ++k) {
        float a = 0.0f;
#pragma unroll
        for (int j = 0; j < HCC; ++j) a += hrow[j] * wcol[k][j];
        ckl[k][t] = a;
      }
    }
  }
  __syncthreads();
  // Clenshaw: bcur = c4, bprev = 0; b_k = alpha*P*bcur - bprev + c_k
  int r0 = 0, r1 = 0;
  if (act) {
    bcur[t] = ckl[4][t];
    r0 = rows[g * NPP + t];
    r1 = rows[g * NPP + t + 1];
  }
  float bprev = 0.0f;
  float v = 0.0f;
  __syncthreads();
#pragma unroll
  for (int step = 0; step < 4; ++step) {
    const float alpha = (step == 3) ? 1.0f : 2.0f;
    const int kidx = 3 - step;
    if (act) {
      float acc = 0.0f;
      for (int e = r0; e < r1; ++e) {
        int2 pk = epak[e];
        acc += __int_as_float(pk.y) * bcur[pk.x];
      }
      v = alpha * acc - bprev + ckl[kidx][t];
    }
    __syncthreads();  // all gathers done before overwriting bcur
    if (act) {
      bprev = bcur[t];  // own slot
      bcur[t] = v;
    }
    __syncthreads();
  }
  // epilogue: tanh, write h, pool column mean
  if (act) {
    float h = tanhf(v + bias[c]);
    if (hout) hout[((size_t)g * NPP + t) * HCC + c] = h;
    bcur[t] = h;
  }
  __syncthreads();
  if (t < 32) {
    float s = 0.0f;
    for (int i = t; i < NPP; i += 32) s += bcur[i];
    part[t] = s;
  }
  __syncthreads();
  if (t == 0) {
    float s = 0.0f;
#pragma unroll
    for (int q = 0; q < 32; ++q) s += part[q];
    emb[g * 96 + L * HCC + c] = s * (1.0f / (float)NPP);
  }
}

// ---------------- big GEMM: fbn @ mlp_w1 (255.7 MB W1 stream) ----------------

__device__ __forceinline__ int tri_S(int i) { return i * 999 - (i * (i - 1)) / 2; }

__global__ void __launch_bounds__(256) k_gemm1(const float* __restrict__ x,
                                               const float* __restrict__ bng,
                                               const float* __restrict__ bnb,
                                               const float* __restrict__ W1,
                                               float* __restrict__ accrep) {
  __shared__ float fbn_s[256][8];
  __shared__ float red[8][128];
  const int tid = threadIdx.x;
  const int c4 = (tid & 31) * 4;
  const int stripe = tid >> 5;
  float acc[8][4];
#pragma unroll
  for (int b = 0; b < 8; ++b)
#pragma unroll
    for (int q = 0; q < 4; ++q) acc[b][q] = 0.0f;

  for (int t = 0; t < 2; ++t) {
    const int j0 = blockIdx.x * 512 + t * 256;
    const int j = j0 + tid;
    float vals[8];
    if (j < TRIN) {
      const float tt = 1999.0f;
      int i = (int)((tt - sqrtf(tt * tt - 8.0f * (float)j)) * 0.5f);
      i = max(0, min(i, 998));
      while (tri_S(i + 1) <= j) ++i;
      while (tri_S(i) > j) --i;
      int i1 = j - tri_S(i) + i + 1;
      size_t base = (size_t)i * FF + i1;
#pragma unroll
      for (int b = 0; b < 8; ++b) vals[b] = x[(size_t)b * (FF * NPP) + base];
      float m = 0.0f;
#pragma unroll
      for (int b = 0; b < 8; ++b) m += vals[b];
      m *= 0.125f;
      float va = 0.0f;
#pragma unroll
      for (int b = 0; b < 8; ++b) { float d = vals[b] - m; va += d * d; }
      va *= 0.125f;
      float sc = bng[j] * rsqrtf(va + EPSV);
      float tb = bnb[j] - m * sc;
#pragma unroll
      for (int b = 0; b < 8; ++b) vals[b] = sc * vals[b] + tb;
    } else {
#pragma unroll
      for (int b = 0; b < 8; ++b) vals[b] = 0.0f;
    }
    __syncthreads();
    *(float4*)&fbn_s[tid][0] = make_float4(vals[0], vals[1], vals[2], vals[3]);
    *(float4*)&fbn_s[tid][4] = make_float4(vals[4], vals[5], vals[6], vals[7]);
    __syncthreads();
    const int jbase = stripe * 32;
    if (j0 + 256 <= TRIN) {
#pragma unroll 8
      for (int jj = jbase; jj < jbase + 32; ++jj) {
        float4 w = *(const float4*)(W1 + (size_t)(j0 + jj) * HID + c4);
        float4 f0 = *(const float4*)&fbn_s[jj][0];
        float4 f1 = *(const float4*)&fbn_s[jj][4];
        float wv[4] = {w.x, w.y, w.z, w.w};
        float fv[8] = {f0.x, f0.y, f0.z, f0.w, f1.x, f1.y, f1.z, f1.w};
#pragma unroll
        for (int b = 0; b < 8; ++b)
#pragma unroll
          for (int q = 0; q < 4; ++q) acc[b][q] += fv[b] * wv[q];
      }
    } else {
      for (int jj = jbase; jj < jbase + 32; ++jj) {
        if (j0 + jj >= TRIN) break;
        float4 w = *(const float4*)(W1 + (size_t)(j0 + jj) * HID + c4);
        float4 f0 = *(const float4*)&fbn_s[jj][0];
        float4 f1 = *(const float4*)&fbn_s[jj][4];
        float wv[4] = {w.x, w.y, w.z, w.w};
        float fv[8] = {f0.x, f0.y, f0.z, f0.w, f1.x, f1.y, f1.z, f1.w};
#pragma unroll
        for (int b = 0; b < 8; ++b)
#pragma unroll
          for (int q = 0; q < 4; ++q) acc[b][q] += fv[b] * wv[q];
      }
    }
  }
#pragma unroll
  for (int b = 0; b < 8; ++b) {
    __syncthreads();
    red[stripe][c4 + 0] = acc[b][0];
    red[stripe][c4 + 1] = acc[b][1];
    red[stripe][c4 + 2] = acc[b][2];
    red[stripe][c4 + 3] = acc[b][3];
    __syncthreads();
    if (tid < 128) {
      float s = 0.0f;
#pragma unroll
      for (int q = 0; q < 8; ++q) s += red[q][tid];
      atomicAdd(&accrep[(blockIdx.x & (NREP - 1)) * 1024 + b * HID + tid], s);
    }
  }
}

// ---------------- MLP tail (+ hbn fused, + replica reduction) ----------------

__global__ void __launch_bounds__(128) k_mlp(
    const float* __restrict__ accrep, const float* __restrict__ emb,
    const float* __restrict__ hg, const float* __restrict__ hb,
    const float* __restrict__ mb1,
    const float* __restrict__ g1, const float* __restrict__ be1,
    const float* __restrict__ W2, const float* __restrict__ mb2,
    const float* __restrict__ g2, const float* __restrict__ be2,
    const float* __restrict__ W3, const float* __restrict__ mb3,
    const float* __restrict__ g3, const float* __restrict__ be3,
    const float* __restrict__ W4, const float* __restrict__ mb4,
    float* __restrict__ out) {
  __shared__ float A[8][128];
  __shared__ float Bm[8][64];
  __shared__ float Cm[8][64];
  __shared__ float lg[8][2];
  int tid = threadIdx.x;
  if (tid < 96) {
    float v[8];
    float m = 0.0f;
#pragma unroll
    for (int q = 0; q < 8; ++q) { v[q] = emb[q * 96 + tid]; m += v[q]; }
    m *= 0.125f;
    float va = 0.0f;
#pragma unroll
    for (int q = 0; q < 8; ++q) { float d = v[q] - m; va += d * d; }
    va *= 0.125f;
    float s = hg[tid] * rsqrtf(va + EPSV);
    float t = hb[tid] - m * s;
#pragma unroll
    for (int q = 0; q < 8; ++q) out[16 + q * 96 + tid] = s * v[q] + t;
  }
  {
    float v[8];
#pragma unroll
    for (int b = 0; b < 8; ++b) {
      float a = mb1[tid];
      for (int rep = 0; rep < NREP; ++rep) a += accrep[rep * 1024 + b * HID + tid];
      v[b] = a;
    }
    float m = 0.0f;
#pragma unroll
    for (int b = 0; b < 8; ++b) m += v[b];
    m *= 0.125f;
    float va = 0.0f;
#pragma unroll
    for (int b = 0; b < 8; ++b) { float d = v[b] - m; va += d * d; }
    va *= 0.125f;
    float s = g1[tid] * rsqrtf(va + EPSV);
    float t = be1[tid] - m * s;
#pragma unroll
    for (int b = 0; b < 8; ++b) {
      float z = s * v[b] + t;
      A[b][tid] = (z > 0.0f) ? z : 0.0f;
    }
  }
  __syncthreads();
  if (tid < 64) {
    float v[8];
#pragma unroll
    for (int b = 0; b < 8; ++b) {
      float a2 = mb2[tid];
      for (int j = 0; j < 128; ++j) a2 += A[b][j] * W2[j * 64 + tid];
      v[b] = a2;
    }
    float m = 0.0f;
#pragma unroll
    for (int b = 0; b < 8; ++b) m += v[b];
    m *= 0.125f;
    float va = 0.0f;
#pragma unroll
    for (int b = 0; b < 8; ++b) { float d = v[b] - m; va += d * d; }
    va *= 0.125f;
    float s = g2[tid] * rsqrtf(va + EPSV);
    float t = be2[tid] - m * s;
#pragma unroll
    for (int b = 0; b < 8; ++b) {
      float z = s * v[b] + t;
      Bm[b][tid] = (z > 0.0f) ? z : 0.0f;
    }
  }
  __syncthreads();
  if (tid < 64) {
    float v[8];
#pragma unroll
    for (int b = 0; b < 8; ++b) {
      float a3 = mb3[tid];
      for (int j = 0; j < 64; ++j) a3 += Bm[b][j] * W3[j * 64 + tid];
      v[b] = a3;
    }
    float m = 0.0f;
#pragma unroll
    for (int b = 0; b < 8; ++b) m += v[b];
    m *= 0.125f;
    float va = 0.0f;
#pragma unroll
    for (int b = 0; b < 8; ++b) { float d = v[b] - m; va += d * d; }
    va *= 0.125f;
    float s = g3[tid] * rsqrtf(va + EPSV);
    float t = be3[tid] - m * s;
#pragma unroll
    for (int b = 0; b < 8; ++b) {
      float z = s * v[b] + t;
      Cm[b][tid] = (z > 0.0f) ? z : 0.0f;
    }
  }
  __syncthreads();
  if (tid < 16) {
    int b = tid >> 1, c = tid & 1;
    float a4 = mb4[c];
    for (int j = 0; j < 64; ++j) a4 += Cm[b][j] * W4[j * 2 + c];
    lg[b][c] = a4;
  }
  __syncthreads();
  if (tid < 8) {
    float l0 = lg[tid][0], l1 = lg[tid][1];
    float mm = fmaxf(l0, l1);
    float lse = mm + logf(expf(l0 - mm) + expf(l1 - mm));
    out[tid * 2 + 0] = l0 - lse;
    out[tid * 2 + 1] = l1 - lse;
  }
}

// ---------------- launch ----------------

extern "C" void kernel_launch(void* const* d_in, const int* in_sizes, int n_in,
                              void* d_out, int out_size, void* d_ws, size_t ws_size,
                              hipStream_t stream) {
  const float* x = (const float*)d_in[0];
  const int* ei = (const int*)d_in[1];
  const int* src = ei;
  const int* dst = ei + EE;
  const float* cw0 = (const float*)d_in[3];
  const float* cb0 = (const float*)d_in[4];
  const float* cw1 = (const float*)d_in[5];
  const float* cb1 = (const float*)d_in[6];
  const float* cw2 = (const float*)d_in[7];
  const float* cb2 = (const float*)d_in[8];
  const float* bnhg = (const float*)d_in[9];
  const float* bnhb = (const float*)d_in[10];
  const float* bng = (const float*)d_in[11];
  const float* bnb = (const float*)d_in[12];
  const float* mw1 = (const float*)d_in[13];
  const float* mb1 = (const float*)d_in[14];
  const float* b1g = (const float*)d_in[15];
  const float* b1b = (const float*)d_in[16];
  const float* mw2 = (const float*)d_in[17];
  const float* mb2 = (const float*)d_in[18];
  const float* b2g = (const float*)d_in[19];
  const float* b2b = (const float*)d_in[20];
  const float* mw3 = (const float*)d_in[21];
  const float* mb3 = (const float*)d_in[22];
  const float* b3g = (const float*)d_in[23];
  const float* b3b = (const float*)d_in[24];
  const float* mw4 = (const float*)d_in[25];
  const float* mb4 = (const float*)d_in[26];

  float* ws = (float*)d_ws;
  int* wsi = (int*)d_ws;
  float* out = (float*)d_out;

  float* accrep = ws + IDX_ACC;
  int* rows = wsi + IDX_ROWS;
  int2* epak = (int2*)(wsi + IDX_EPAK);
  float* h1 = ws + IDX_H1;
  float* h2 = ws + IDX_H2;
  float* emb = ws + IDX_EMB;

  hipMemsetAsync(accrep, 0, NREP * 1024 * sizeof(float), stream);

  k_gemm1<<<976, 256, 0, stream>>>(x, bng, bnb, mw1, accrep);
  k_prep<<<1, 1024, 0, stream>>>(src, dst, rows, epak);
  k_layer<<<256, 1024, 0, stream>>>(cw0, cb0, nullptr, h1, rows, epak, emb, 0);
  k_layer<<<256, 1024, 0, stream>>>(cw1, cb1, h1, h2, rows, epak, emb, 1);
  k_layer<<<256, 1024, 0, stream>>>(cw2, cb2, h2, nullptr, rows, epak, emb, 2);
  k_mlp<<<1, 128, 0, stream>>>(accrep, emb, bnhg, bnhb, mb1, b1g, b1b,
                               mw2, mb2, b2g, b2b, mw3, mb3, b3g, b3b,
                               mw4, mb4, out);
}

// Round 4
// 591.790 us; speedup vs baseline: 1.1785x; 1.1785x over previous
//
#include <hip/hip_runtime.h>

#define NN 8000
#define NPP 1000
#define FF 1000
#define HCC 32
#define KK 5
#define EE 80000
#define TRIN 499500
#define HID 128
#define EPSV 1e-5f
#define NREP 64

// workspace layout (4-byte units)
#define IDX_ACC  0          // NREP x 1024 fp32 (zeroed)
#define IDX_DEGI 65536      // 8000 ints (zeroed)
#define IDX_CNT  73536      // 8000 ints (zeroed)
#define IDX_FILL 81536      // 8000 ints (zeroed)
#define ZERO_N   89536      // one memset covers [0, ZERO_N)
#define IDX_ROWS 89600      // 8001 ints
#define IDX_EPAK 97664      // 80000 int2
#define IDX_H1   257664     // 8000*32 fp32
#define IDX_H2   513664     // 8000*32 fp32
#define IDX_EMB  769664     // 768 fp32 (direct stores)

// ---------------- graph preprocessing (grid-parallel) ----------------

__global__ void k_count(const int* __restrict__ src, const int* __restrict__ dst,
                        int* __restrict__ degi, int* __restrict__ cnt) {
  int e = blockIdx.x * blockDim.x + threadIdx.x;
  if (e >= EE) return;
  atomicAdd(&degi[src[e]], 1);
  atomicAdd(&cnt[dst[e]], 1);
}

__global__ void k_scan(const int* __restrict__ cnt, int* __restrict__ rows) {
  __shared__ int ssum[1024];
  int tid = threadIdx.x;
  int base = tid * 8;
  int loc[8];
  int s = 0;
#pragma unroll
  for (int q = 0; q < 8; ++q) {
    int idx = base + q;
    int v = (idx < NN) ? cnt[idx] : 0;
    loc[q] = s;
    s += v;
  }
  ssum[tid] = s;
  __syncthreads();
  for (int d = 1; d < 1024; d <<= 1) {
    int v = (tid >= d) ? ssum[tid - d] : 0;
    __syncthreads();
    ssum[tid] += v;
    __syncthreads();
  }
  int off = (tid == 0) ? 0 : ssum[tid - 1];
#pragma unroll
  for (int q = 0; q < 8; ++q) {
    int idx = base + q;
    if (idx < NN) rows[idx] = off + loc[q];
  }
  if (tid == 1023) rows[NN] = EE;
}

// fill CSR as packed int2{src%NPP, weight bits}; weight from degrees inline
__global__ void k_fill(const int* __restrict__ src, const int* __restrict__ dst,
                       const int* __restrict__ degi, const int* __restrict__ rows,
                       int* __restrict__ fill, int2* __restrict__ epak) {
  int e = blockIdx.x * blockDim.x + threadIdx.x;
  if (e >= EE) return;
  int s = src[e], d = dst[e];
  int pos = rows[d] + atomicAdd(&fill[d], 1);
  int dd = degi[d];
  float w = -rsqrtf((float)degi[s]) * ((dd > 0) ? rsqrtf((float)dd) : 0.0f);
  int2 pk;
  pk.x = s % NPP;
  pk.y = __float_as_int(w);
  epak[pos] = pk;
}

// ---------------- fused Chebyshev layer (Clenshaw, LDS-resident) ----------------
// one workgroup per (graph g, column c); 1024 threads, thread t owns row t.
// hin == null  -> layer-0: ck[k][i] = cw[k][i][c]   (identity input, tiled)
// hin != null  -> ck[k][i] = sum_j hin[g,i,j] * cw[k][j][c]
// 4 Clenshaw steps entirely in LDS; h -> hout (if any) + column mean -> emb.
__global__ void __launch_bounds__(1024, 4) k_layer(
    const float* __restrict__ cw, const float* __restrict__ bias,
    const float* __restrict__ hin, float* __restrict__ hout,
    const int* __restrict__ rows, const int2* __restrict__ epak,
    float* __restrict__ emb, int L) {
  __shared__ float ckl[KK][NPP];
  __shared__ float bcur[NPP];
  __shared__ float wcol[KK][HCC];
  __shared__ float part[32];
  const int t = threadIdx.x;
  const int g = blockIdx.x >> 5;
  const int c = blockIdx.x & 31;
  const bool act = t < NPP;
  if (hin == nullptr) {
    if (act) {
#pragma unroll
      for (int k = 0; k < KK; ++k)
        ckl[k][t] = cw[k * (FF * HCC) + t * HCC + c];
    }
  } else {
    if (t < KK * HCC) {
      int k = t >> 5, j = t & 31;
      wcol[k][j] = cw[k * (HCC * HCC) + j * HCC + c];
    }
    __syncthreads();
    if (act) {
      float hrow[HCC];
      const float* hp = hin + ((size_t)g * NPP + t) * HCC;
#pragma unroll
      for (int q = 0; q < HCC / 4; ++q) {
        float4 f = *(const float4*)(hp + q * 4);
        hrow[q * 4 + 0] = f.x; hrow[q * 4 + 1] = f.y;
        hrow[q * 4 + 2] = f.z; hrow[q * 4 + 3] = f.w;
      }
#pragma unroll
      for (int k = 0; k < KK; ++k) {
        float a = 0.0f;
#pragma unroll
        for (int j = 0; j < HCC; ++j) a += hrow[j] * wcol[k][j];
        ckl[k][t] = a;
      }
    }
  }
  __syncthreads();
  int r0 = 0, r1 = 0;
  if (act) {
    bcur[t] = ckl[4][t];
    r0 = rows[g * NPP + t];
    r1 = rows[g * NPP + t + 1];
  }
  float bprev = 0.0f;
  float v = 0.0f;
  __syncthreads();
#pragma unroll
  for (int step = 0; step < 4; ++step) {
    const float alpha = (step == 3) ? 1.0f : 2.0f;
    const int kidx = 3 - step;
    if (act) {
      float acc = 0.0f;
      for (int e = r0; e < r1; ++e) {
        int2 pk = epak[e];
        acc += __int_as_float(pk.y) * bcur[pk.x];
      }
      v = alpha * acc - bprev + ckl[kidx][t];
    }
    __syncthreads();
    if (act) {
      bprev = bcur[t];
      bcur[t] = v;
    }
    __syncthreads();
  }
  if (act) {
    float h = tanhf(v + bias[c]);
    if (hout) hout[((size_t)g * NPP + t) * HCC + c] = h;
    bcur[t] = h;
  }
  __syncthreads();
  if (t < 32) {
    float s = 0.0f;
    for (int i = t; i < NPP; i += 32) s += bcur[i];
    part[t] = s;
  }
  __syncthreads();
  if (t == 0) {
    float s = 0.0f;
#pragma unroll
    for (int q = 0; q < 32; ++q) s += part[q];
    emb[g * 96 + L * HCC + c] = s * (1.0f / (float)NPP);
  }
}

// ---------------- big GEMM: fbn @ mlp_w1 (255.7 MB W1 stream) ----------------

__device__ __forceinline__ int tri_S(int i) { return i * 999 - (i * (i - 1)) / 2; }

__global__ void __launch_bounds__(256) k_gemm1(const float* __restrict__ x,
                                               const float* __restrict__ bng,
                                               const float* __restrict__ bnb,
                                               const float* __restrict__ W1,
                                               float* __restrict__ accrep) {
  __shared__ float fbn_s[256][8];
  __shared__ float red[8][128];
  const int tid = threadIdx.x;
  const int c4 = (tid & 31) * 4;
  const int stripe = tid >> 5;
  float acc[8][4];
#pragma unroll
  for (int b = 0; b < 8; ++b)
#pragma unroll
    for (int q = 0; q < 4; ++q) acc[b][q] = 0.0f;

  for (int t = 0; t < 2; ++t) {
    const int j0 = blockIdx.x * 512 + t * 256;
    const int j = j0 + tid;
    float vals[8];
    if (j < TRIN) {
      const float tt = 1999.0f;
      int i = (int)((tt - sqrtf(tt * tt - 8.0f * (float)j)) * 0.5f);
      i = max(0, min(i, 998));
      while (tri_S(i + 1) <= j) ++i;
      while (tri_S(i) > j) --i;
      int i1 = j - tri_S(i) + i + 1;
      size_t base = (size_t)i * FF + i1;
#pragma unroll
      for (int b = 0; b < 8; ++b) vals[b] = x[(size_t)b * (FF * NPP) + base];
      float m = 0.0f;
#pragma unroll
      for (int b = 0; b < 8; ++b) m += vals[b];
      m *= 0.125f;
      float va = 0.0f;
#pragma unroll
      for (int b = 0; b < 8; ++b) { float d = vals[b] - m; va += d * d; }
      va *= 0.125f;
      float sc = bng[j] * rsqrtf(va + EPSV);
      float tb = bnb[j] - m * sc;
#pragma unroll
      for (int b = 0; b < 8; ++b) vals[b] = sc * vals[b] + tb;
    } else {
#pragma unroll
      for (int b = 0; b < 8; ++b) vals[b] = 0.0f;
    }
    __syncthreads();
    *(float4*)&fbn_s[tid][0] = make_float4(vals[0], vals[1], vals[2], vals[3]);
    *(float4*)&fbn_s[tid][4] = make_float4(vals[4], vals[5], vals[6], vals[7]);
    __syncthreads();
    const int jbase = stripe * 32;
    if (j0 + 256 <= TRIN) {
#pragma unroll 8
      for (int jj = jbase; jj < jbase + 32; ++jj) {
        float4 w = *(const float4*)(W1 + (size_t)(j0 + jj) * HID + c4);
        float4 f0 = *(const float4*)&fbn_s[jj][0];
        float4 f1 = *(const float4*)&fbn_s[jj][4];
        float wv[4] = {w.x, w.y, w.z, w.w};
        float fv[8] = {f0.x, f0.y, f0.z, f0.w, f1.x, f1.y, f1.z, f1.w};
#pragma unroll
        for (int b = 0; b < 8; ++b)
#pragma unroll
          for (int q = 0; q < 4; ++q) acc[b][q] += fv[b] * wv[q];
      }
    } else {
      for (int jj = jbase; jj < jbase + 32; ++jj) {
        if (j0 + jj >= TRIN) break;
        float4 w = *(const float4*)(W1 + (size_t)(j0 + jj) * HID + c4);
        float4 f0 = *(const float4*)&fbn_s[jj][0];
        float4 f1 = *(const float4*)&fbn_s[jj][4];
        float wv[4] = {w.x, w.y, w.z, w.w};
        float fv[8] = {f0.x, f0.y, f0.z, f0.w, f1.x, f1.y, f1.z, f1.w};
#pragma unroll
        for (int b = 0; b < 8; ++b)
#pragma unroll
          for (int q = 0; q < 4; ++q) acc[b][q] += fv[b] * wv[q];
      }
    }
  }
#pragma unroll
  for (int b = 0; b < 8; ++b) {
    __syncthreads();
    red[stripe][c4 + 0] = acc[b][0];
    red[stripe][c4 + 1] = acc[b][1];
    red[stripe][c4 + 2] = acc[b][2];
    red[stripe][c4 + 3] = acc[b][3];
    __syncthreads();
    if (tid < 128) {
      float s = 0.0f;
#pragma unroll
      for (int q = 0; q < 8; ++q) s += red[q][tid];
      atomicAdd(&accrep[(blockIdx.x & (NREP - 1)) * 1024 + b * HID + tid], s);
    }
  }
}

// ---------------- MLP tail (+ hbn fused, + replica reduction) ----------------

__global__ void __launch_bounds__(128) k_mlp(
    const float* __restrict__ accrep, const float* __restrict__ emb,
    const float* __restrict__ hg, const float* __restrict__ hb,
    const float* __restrict__ mb1,
    const float* __restrict__ g1, const float* __restrict__ be1,
    const float* __restrict__ W2, const float* __restrict__ mb2,
    const float* __restrict__ g2, const float* __restrict__ be2,
    const float* __restrict__ W3, const float* __restrict__ mb3,
    const float* __restrict__ g3, const float* __restrict__ be3,
    const float* __restrict__ W4, const float* __restrict__ mb4,
    float* __restrict__ out) {
  __shared__ float A[8][128];
  __shared__ float Bm[8][64];
  __shared__ float Cm[8][64];
  __shared__ float lg[8][2];
  int tid = threadIdx.x;
  if (tid < 96) {
    float v[8];
    float m = 0.0f;
#pragma unroll
    for (int q = 0; q < 8; ++q) { v[q] = emb[q * 96 + tid]; m += v[q]; }
    m *= 0.125f;
    float va = 0.0f;
#pragma unroll
    for (int q = 0; q < 8; ++q) { float d = v[q] - m; va += d * d; }
    va *= 0.125f;
    float s = hg[tid] * rsqrtf(va + EPSV);
    float t = hb[tid] - m * s;
#pragma unroll
    for (int q = 0; q < 8; ++q) out[16 + q * 96 + tid] = s * v[q] + t;
  }
  {
    float v[8];
#pragma unroll
    for (int b = 0; b < 8; ++b) {
      float a = mb1[tid];
      for (int rep = 0; rep < NREP; ++rep) a += accrep[rep * 1024 + b * HID + tid];
      v[b] = a;
    }
    float m = 0.0f;
#pragma unroll
    for (int b = 0; b < 8; ++b) m += v[b];
    m *= 0.125f;
    float va = 0.0f;
#pragma unroll
    for (int b = 0; b < 8; ++b) { float d = v[b] - m; va += d * d; }
    va *= 0.125f;
    float s = g1[tid] * rsqrtf(va + EPSV);
    float t = be1[tid] - m * s;
#pragma unroll
    for (int b = 0; b < 8; ++b) {
      float z = s * v[b] + t;
      A[b][tid] = (z > 0.0f) ? z : 0.0f;
    }
  }
  __syncthreads();
  if (tid < 64) {
    float v[8];
#pragma unroll
    for (int b = 0; b < 8; ++b) {
      float a2 = mb2[tid];
      for (int j = 0; j < 128; ++j) a2 += A[b][j] * W2[j * 64 + tid];
      v[b] = a2;
    }
    float m = 0.0f;
#pragma unroll
    for (int b = 0; b < 8; ++b) m += v[b];
    m *= 0.125f;
    float va = 0.0f;
#pragma unroll
    for (int b = 0; b < 8; ++b) { float d = v[b] - m; va += d * d; }
    va *= 0.125f;
    float s = g2[tid] * rsqrtf(va + EPSV);
    float t = be2[tid] - m * s;
#pragma unroll
    for (int b = 0; b < 8; ++b) {
      float z = s * v[b] + t;
      Bm[b][tid] = (z > 0.0f) ? z : 0.0f;
    }
  }
  __syncthreads();
  if (tid < 64) {
    float v[8];
#pragma unroll
    for (int b = 0; b < 8; ++b) {
      float a3 = mb3[tid];
      for (int j = 0; j < 64; ++j) a3 += Bm[b][j] * W3[j * 64 + tid];
      v[b] = a3;
    }
    float m = 0.0f;
#pragma unroll
    for (int b = 0; b < 8; ++b) m += v[b];
    m *= 0.125f;
    float va = 0.0f;
#pragma unroll
    for (int b = 0; b < 8; ++b) { float d = v[b] - m; va += d * d; }
    va *= 0.125f;
    float s = g3[tid] * rsqrtf(va + EPSV);
    float t = be3[tid] - m * s;
#pragma unroll
    for (int b = 0; b < 8; ++b) {
      float z = s * v[b] + t;
      Cm[b][tid] = (z > 0.0f) ? z : 0.0f;
    }
  }
  __syncthreads();
  if (tid < 16) {
    int b = tid >> 1, c = tid & 1;
    float a4 = mb4[c];
    for (int j = 0; j < 64; ++j) a4 += Cm[b][j] * W4[j * 2 + c];
    lg[b][c] = a4;
  }
  __syncthreads();
  if (tid < 8) {
    float l0 = lg[tid][0], l1 = lg[tid][1];
    float mm = fmaxf(l0, l1);
    float lse = mm + logf(expf(l0 - mm) + expf(l1 - mm));
    out[tid * 2 + 0] = l0 - lse;
    out[tid * 2 + 1] = l1 - lse;
  }
}

// ---------------- launch ----------------

extern "C" void kernel_launch(void* const* d_in, const int* in_sizes, int n_in,
                              void* d_out, int out_size, void* d_ws, size_t ws_size,
                              hipStream_t stream) {
  const float* x = (const float*)d_in[0];
  const int* ei = (const int*)d_in[1];
  const int* src = ei;
  const int* dst = ei + EE;
  const float* cw0 = (const float*)d_in[3];
  const float* cb0 = (const float*)d_in[4];
  const float* cw1 = (const float*)d_in[5];
  const float* cb1 = (const float*)d_in[6];
  const float* cw2 = (const float*)d_in[7];
  const float* cb2 = (const float*)d_in[8];
  const float* bnhg = (const float*)d_in[9];
  const float* bnhb = (const float*)d_in[10];
  const float* bng = (const float*)d_in[11];
  const float* bnb = (const float*)d_in[12];
  const float* mw1 = (const float*)d_in[13];
  const float* mb1 = (const float*)d_in[14];
  const float* b1g = (const float*)d_in[15];
  const float* b1b = (const float*)d_in[16];
  const float* mw2 = (const float*)d_in[17];
  const float* mb2 = (const float*)d_in[18];
  const float* b2g = (const float*)d_in[19];
  const float* b2b = (const float*)d_in[20];
  const float* mw3 = (const float*)d_in[21];
  const float* mb3 = (const float*)d_in[22];
  const float* b3g = (const float*)d_in[23];
  const float* b3b = (const float*)d_in[24];
  const float* mw4 = (const float*)d_in[25];
  const float* mb4 = (const float*)d_in[26];

  float* ws = (float*)d_ws;
  int* wsi = (int*)d_ws;
  float* out = (float*)d_out;

  float* accrep = ws + IDX_ACC;
  int* degi = wsi + IDX_DEGI;
  int* cnt = wsi + IDX_CNT;
  int* fill = wsi + IDX_FILL;
  int* rows = wsi + IDX_ROWS;
  int2* epak = (int2*)(wsi + IDX_EPAK);
  float* h1 = ws + IDX_H1;
  float* h2 = ws + IDX_H2;
  float* emb = ws + IDX_EMB;

  hipMemsetAsync(wsi, 0, ZERO_N * sizeof(int), stream);

  k_gemm1<<<976, 256, 0, stream>>>(x, bng, bnb, mw1, accrep);
  k_count<<<(EE + 255) / 256, 256, 0, stream>>>(src, dst, degi, cnt);
  k_scan<<<1, 1024, 0, stream>>>(cnt, rows);
  k_fill<<<(EE + 255) / 256, 256, 0, stream>>>(src, dst, degi, rows, fill, epak);
  k_layer<<<256, 1024, 0, stream>>>(cw0, cb0, nullptr, h1, rows, epak, emb, 0);
  k_layer<<<256, 1024, 0, stream>>>(cw1, cb1, h1, h2, rows, epak, emb, 1);
  k_layer<<<256, 1024, 0, stream>>>(cw2, cb2, h2, nullptr, rows, epak, emb, 2);
  k_mlp<<<1, 128, 0, stream>>>(accrep, emb, bnhg, bnhb, mb1, b1g, b1b,
                               mw2, mb2, b2g, b2b, mw3, mb3, b3g, b3b,
                               mw4, mb4, out);
}

// Round 5
// 563.984 us; speedup vs baseline: 1.2366x; 1.0493x over previous
//
#include <hip/hip_runtime.h>

#define NN 8000
#define NPP 1000
#define FF 1000
#define HCC 32
#define KK 5
#define EE 80000
#define TRIN 499500
#define HID 128
#define EPSV 1e-5f
#define NREP 64

// workspace layout (4-byte units)
#define IDX_ACC  0          // NREP x 1024 fp32 (zeroed)
#define IDX_DEGI 65536      // 8000 ints (zeroed)
#define IDX_CNT  73536      // 8000 ints (zeroed)
#define IDX_FILL 81536      // 8000 ints (zeroed)
#define ZERO_N   89536      // one memset covers [0, ZERO_N)
#define IDX_ROWS 89600      // 8001 ints
#define IDX_EPAK 97664      // 80000 int2
#define IDX_H1   257664     // 8000*32 fp32
#define IDX_H2   513664     // 8000*32 fp32
#define IDX_EMB  769664     // 768 fp32 (direct stores)

// ---------------- graph preprocessing (grid-parallel) ----------------

__global__ void k_count(const int* __restrict__ src, const int* __restrict__ dst,
                        int* __restrict__ degi, int* __restrict__ cnt) {
  int e = blockIdx.x * blockDim.x + threadIdx.x;
  if (e >= EE) return;
  atomicAdd(&degi[src[e]], 1);
  atomicAdd(&cnt[dst[e]], 1);
}

__global__ void k_scan(const int* __restrict__ cnt, int* __restrict__ rows) {
  __shared__ int ssum[1024];
  int tid = threadIdx.x;
  int base = tid * 8;
  int loc[8];
  int s = 0;
#pragma unroll
  for (int q = 0; q < 8; ++q) {
    int idx = base + q;
    int v = (idx < NN) ? cnt[idx] : 0;
    loc[q] = s;
    s += v;
  }
  ssum[tid] = s;
  __syncthreads();
  for (int d = 1; d < 1024; d <<= 1) {
    int v = (tid >= d) ? ssum[tid - d] : 0;
    __syncthreads();
    ssum[tid] += v;
    __syncthreads();
  }
  int off = (tid == 0) ? 0 : ssum[tid - 1];
#pragma unroll
  for (int q = 0; q < 8; ++q) {
    int idx = base + q;
    if (idx < NN) rows[idx] = off + loc[q];
  }
  if (tid == 1023) rows[NN] = EE;
}

__global__ void k_fill(const int* __restrict__ src, const int* __restrict__ dst,
                       const int* __restrict__ degi, const int* __restrict__ rows,
                       int* __restrict__ fill, int2* __restrict__ epak) {
  int e = blockIdx.x * blockDim.x + threadIdx.x;
  if (e >= EE) return;
  int s = src[e], d = dst[e];
  int pos = rows[d] + atomicAdd(&fill[d], 1);
  int dd = degi[d];
  float w = -rsqrtf((float)degi[s]) * ((dd > 0) ? rsqrtf((float)dd) : 0.0f);
  int2 pk;
  pk.x = s % NPP;
  pk.y = __float_as_int(w);
  epak[pos] = pk;
}

// ---------------- fused Chebyshev layer (Clenshaw, LDS-resident) ----------------
__global__ void __launch_bounds__(1024, 4) k_layer(
    const float* __restrict__ cw, const float* __restrict__ bias,
    const float* __restrict__ hin, float* __restrict__ hout,
    const int* __restrict__ rows, const int2* __restrict__ epak,
    float* __restrict__ emb, int L) {
  __shared__ float ckl[KK][NPP];
  __shared__ float bcur[NPP];
  __shared__ float wcol[KK][HCC];
  __shared__ float part[32];
  const int t = threadIdx.x;
  const int g = blockIdx.x >> 5;
  const int c = blockIdx.x & 31;
  const bool act = t < NPP;
  if (hin == nullptr) {
    if (act) {
#pragma unroll
      for (int k = 0; k < KK; ++k)
        ckl[k][t] = cw[k * (FF * HCC) + t * HCC + c];
    }
  } else {
    if (t < KK * HCC) {
      int k = t >> 5, j = t & 31;
      wcol[k][j] = cw[k * (HCC * HCC) + j * HCC + c];
    }
    __syncthreads();
    if (act) {
      float hrow[HCC];
      const float* hp = hin + ((size_t)g * NPP + t) * HCC;
#pragma unroll
      for (int q = 0; q < HCC / 4; ++q) {
        float4 f = *(const float4*)(hp + q * 4);
        hrow[q * 4 + 0] = f.x; hrow[q * 4 + 1] = f.y;
        hrow[q * 4 + 2] = f.z; hrow[q * 4 + 3] = f.w;
      }
#pragma unroll
      for (int k = 0; k < KK; ++k) {
        float a = 0.0f;
#pragma unroll
        for (int j = 0; j < HCC; ++j) a += hrow[j] * wcol[k][j];
        ckl[k][t] = a;
      }
    }
  }
  __syncthreads();
  int r0 = 0, r1 = 0;
  if (act) {
    bcur[t] = ckl[4][t];
    r0 = rows[g * NPP + t];
    r1 = rows[g * NPP + t + 1];
  }
  float bprev = 0.0f;
  float v = 0.0f;
  __syncthreads();
#pragma unroll
  for (int step = 0; step < 4; ++step) {
    const float alpha = (step == 3) ? 1.0f : 2.0f;
    const int kidx = 3 - step;
    if (act) {
      float acc = 0.0f;
      for (int e = r0; e < r1; ++e) {
        int2 pk = epak[e];
        acc += __int_as_float(pk.y) * bcur[pk.x];
      }
      v = alpha * acc - bprev + ckl[kidx][t];
    }
    __syncthreads();
    if (act) {
      bprev = bcur[t];
      bcur[t] = v;
    }
    __syncthreads();
  }
  if (act) {
    float h = tanhf(v + bias[c]);
    if (hout) hout[((size_t)g * NPP + t) * HCC + c] = h;
    bcur[t] = h;
  }
  __syncthreads();
  if (t < 32) {
    float s = 0.0f;
    for (int i = t; i < NPP; i += 32) s += bcur[i];
    part[t] = s;
  }
  __syncthreads();
  if (t == 0) {
    float s = 0.0f;
#pragma unroll
    for (int q = 0; q < 32; ++q) s += part[q];
    emb[g * 96 + L * HCC + c] = s * (1.0f / (float)NPP);
  }
}

// ---------------- big GEMM: fbn @ mlp_w1 (255.7 MB W1 stream) ----------------
// one 256-j tile per block; grid 1952 -> ~7.6 blocks/CU (balanced)

__device__ __forceinline__ int tri_S(int i) { return i * 999 - (i * (i - 1)) / 2; }

__global__ void __launch_bounds__(256) k_gemm1(const float* __restrict__ x,
                                               const float* __restrict__ bng,
                                               const float* __restrict__ bnb,
                                               const float* __restrict__ W1,
                                               float* __restrict__ accrep) {
  __shared__ float fbn_s[256][8];
  __shared__ float red[8][128];
  const int tid = threadIdx.x;
  const int c4 = (tid & 31) * 4;
  const int stripe = tid >> 5;
  const int j0 = blockIdx.x * 256;
  float acc[8][4];
#pragma unroll
  for (int b = 0; b < 8; ++b)
#pragma unroll
    for (int q = 0; q < 4; ++q) acc[b][q] = 0.0f;

  {
    const int j = j0 + tid;
    float vals[8];
    if (j < TRIN) {
      const float tt = 1999.0f;
      int i = (int)((tt - sqrtf(tt * tt - 8.0f * (float)j)) * 0.5f);
      i = max(0, min(i, 998));
      while (tri_S(i + 1) <= j) ++i;
      while (tri_S(i) > j) --i;
      int i1 = j - tri_S(i) + i + 1;
      size_t base = (size_t)i * FF + i1;
#pragma unroll
      for (int b = 0; b < 8; ++b) vals[b] = x[(size_t)b * (FF * NPP) + base];
      float m = 0.0f;
#pragma unroll
      for (int b = 0; b < 8; ++b) m += vals[b];
      m *= 0.125f;
      float va = 0.0f;
#pragma unroll
      for (int b = 0; b < 8; ++b) { float d = vals[b] - m; va += d * d; }
      va *= 0.125f;
      float sc = bng[j] * rsqrtf(va + EPSV);
      float tb = bnb[j] - m * sc;
#pragma unroll
      for (int b = 0; b < 8; ++b) vals[b] = sc * vals[b] + tb;
    } else {
#pragma unroll
      for (int b = 0; b < 8; ++b) vals[b] = 0.0f;
    }
    *(float4*)&fbn_s[tid][0] = make_float4(vals[0], vals[1], vals[2], vals[3]);
    *(float4*)&fbn_s[tid][4] = make_float4(vals[4], vals[5], vals[6], vals[7]);
  }
  __syncthreads();

  const int jbase = stripe * 32;
  const int jmax = min(32, TRIN - j0 - jbase);  // <=0 for tail stripes
  const float* wp = W1 + (size_t)(j0 + jbase) * HID + c4;
  if (jmax == 32) {
#pragma unroll 4
    for (int jj = 0; jj < 32; ++jj) {
      float4 w = *(const float4*)(wp + (size_t)jj * HID);
      float4 f0 = *(const float4*)&fbn_s[jbase + jj][0];
      float4 f1 = *(const float4*)&fbn_s[jbase + jj][4];
      float wv[4] = {w.x, w.y, w.z, w.w};
      float fv[8] = {f0.x, f0.y, f0.z, f0.w, f1.x, f1.y, f1.z, f1.w};
#pragma unroll
      for (int b = 0; b < 8; ++b)
#pragma unroll
        for (int q = 0; q < 4; ++q) acc[b][q] += fv[b] * wv[q];
    }
  } else {
    for (int jj = 0; jj < jmax; ++jj) {
      float4 w = *(const float4*)(wp + (size_t)jj * HID);
      float4 f0 = *(const float4*)&fbn_s[jbase + jj][0];
      float4 f1 = *(const float4*)&fbn_s[jbase + jj][4];
      float wv[4] = {w.x, w.y, w.z, w.w};
      float fv[8] = {f0.x, f0.y, f0.z, f0.w, f1.x, f1.y, f1.z, f1.w};
#pragma unroll
      for (int b = 0; b < 8; ++b)
#pragma unroll
        for (int q = 0; q < 4; ++q) acc[b][q] += fv[b] * wv[q];
    }
  }
#pragma unroll
  for (int b = 0; b < 8; ++b) {
    __syncthreads();
    red[stripe][c4 + 0] = acc[b][0];
    red[stripe][c4 + 1] = acc[b][1];
    red[stripe][c4 + 2] = acc[b][2];
    red[stripe][c4 + 3] = acc[b][3];
    __syncthreads();
    if (tid < 128) {
      float s = 0.0f;
#pragma unroll
      for (int q = 0; q < 8; ++q) s += red[q][tid];
      atomicAdd(&accrep[(blockIdx.x & (NREP - 1)) * 1024 + b * HID + tid], s);
    }
  }
}

// ---------------- MLP tail (+ hbn fused), b-parallel, 1024 threads ----------------

__global__ void __launch_bounds__(1024) k_mlp(
    const float* __restrict__ accrep, const float* __restrict__ emb,
    const float* __restrict__ hg, const float* __restrict__ hb,
    const float* __restrict__ mb1,
    const float* __restrict__ g1, const float* __restrict__ be1,
    const float* __restrict__ W2, const float* __restrict__ mb2,
    const float* __restrict__ g2, const float* __restrict__ be2,
    const float* __restrict__ W3, const float* __restrict__ mb3,
    const float* __restrict__ g3, const float* __restrict__ be3,
    const float* __restrict__ W4, const float* __restrict__ mb4,
    float* __restrict__ out) {
  __shared__ float A[8][128];
  __shared__ float V[8][128];
  __shared__ float Bm[8][64];
  __shared__ float Cm[8][64];
  __shared__ float lg[8][2];
  const int tid = threadIdx.x;
  // hbn head (independent; writes out[16:784])
  if (tid < 96) {
    float v[8];
    float m = 0.0f;
#pragma unroll
    for (int q = 0; q < 8; ++q) { v[q] = emb[q * 96 + tid]; m += v[q]; }
    m *= 0.125f;
    float va = 0.0f;
#pragma unroll
    for (int q = 0; q < 8; ++q) { float d = v[q] - m; va += d * d; }
    va *= 0.125f;
    float s = hg[tid] * rsqrtf(va + EPSV);
    float t = hb[tid] - m * s;
#pragma unroll
    for (int q = 0; q < 8; ++q) out[16 + q * 96 + tid] = s * v[q] + t;
  }
  // stage 1: replica reduction (coalesced), thread = (b, c)
  {
    const int c = tid & 127;
    const int b = tid >> 7;
    float a = mb1[c];
    for (int rep = 0; rep < NREP; ++rep) a += accrep[rep * 1024 + tid];
    V[b][c] = a;
  }
  __syncthreads();
  {
    const int c = tid & 127;
    const int b = tid >> 7;
    float m = 0.0f;
#pragma unroll
    for (int q = 0; q < 8; ++q) m += V[q][c];
    m *= 0.125f;
    float va = 0.0f;
#pragma unroll
    for (int q = 0; q < 8; ++q) { float d = V[q][c] - m; va += d * d; }
    va *= 0.125f;
    float s = g1[c] * rsqrtf(va + EPSV);
    float t = be1[c] - m * s;
    float z = s * V[b][c] + t;
    A[b][c] = (z > 0.0f) ? z : 0.0f;
  }
  __syncthreads();
  // stage 2: thread = (b, c2), tid < 512
  if (tid < 512) {
    const int c = tid & 63;
    const int b = tid >> 6;
    float a = mb2[c];
    for (int j = 0; j < 128; ++j) a += A[b][j] * W2[j * 64 + c];
    V[b][c] = a;
  }
  __syncthreads();
  if (tid < 512) {
    const int c = tid & 63;
    const int b = tid >> 6;
    float m = 0.0f;
#pragma unroll
    for (int q = 0; q < 8; ++q) m += V[q][c];
    m *= 0.125f;
    float va = 0.0f;
#pragma unroll
    for (int q = 0; q < 8; ++q) { float d = V[q][c] - m; va += d * d; }
    va *= 0.125f;
    float s = g2[c] * rsqrtf(va + EPSV);
    float t = be2[c] - m * s;
    float z = s * V[b][c] + t;
    Bm[b][c] = (z > 0.0f) ? z : 0.0f;
  }
  __syncthreads();
  // stage 3
  if (tid < 512) {
    const int c = tid & 63;
    const int b = tid >> 6;
    float a = mb3[c];
    for (int j = 0; j < 64; ++j) a += Bm[b][j] * W3[j * 64 + c];
    V[b][c] = a;
  }
  __syncthreads();
  if (tid < 512) {
    const int c = tid & 63;
    const int b = tid >> 6;
    float m = 0.0f;
#pragma unroll
    for (int q = 0; q < 8; ++q) m += V[q][c];
    m *= 0.125f;
    float va = 0.0f;
#pragma unroll
    for (int q = 0; q < 8; ++q) { float d = V[q][c] - m; va += d * d; }
    va *= 0.125f;
    float s = g3[c] * rsqrtf(va + EPSV);
    float t = be3[c] - m * s;
    float z = s * V[b][c] + t;
    Cm[b][c] = (z > 0.0f) ? z : 0.0f;
  }
  __syncthreads();
  if (tid < 16) {
    int b = tid >> 1, c = tid & 1;
    float a4 = mb4[c];
    for (int j = 0; j < 64; ++j) a4 += Cm[b][j] * W4[j * 2 + c];
    lg[b][c] = a4;
  }
  __syncthreads();
  if (tid < 8) {
    float l0 = lg[tid][0], l1 = lg[tid][1];
    float mm = fmaxf(l0, l1);
    float lse = mm + logf(expf(l0 - mm) + expf(l1 - mm));
    out[tid * 2 + 0] = l0 - lse;
    out[tid * 2 + 1] = l1 - lse;
  }
}

// ---------------- launch ----------------

extern "C" void kernel_launch(void* const* d_in, const int* in_sizes, int n_in,
                              void* d_out, int out_size, void* d_ws, size_t ws_size,
                              hipStream_t stream) {
  const float* x = (const float*)d_in[0];
  const int* ei = (const int*)d_in[1];
  const int* src = ei;
  const int* dst = ei + EE;
  const float* cw0 = (const float*)d_in[3];
  const float* cb0 = (const float*)d_in[4];
  const float* cw1 = (const float*)d_in[5];
  const float* cb1 = (const float*)d_in[6];
  const float* cw2 = (const float*)d_in[7];
  const float* cb2 = (const float*)d_in[8];
  const float* bnhg = (const float*)d_in[9];
  const float* bnhb = (const float*)d_in[10];
  const float* bng = (const float*)d_in[11];
  const float* bnb = (const float*)d_in[12];
  const float* mw1 = (const float*)d_in[13];
  const float* mb1 = (const float*)d_in[14];
  const float* b1g = (const float*)d_in[15];
  const float* b1b = (const float*)d_in[16];
  const float* mw2 = (const float*)d_in[17];
  const float* mb2 = (const float*)d_in[18];
  const float* b2g = (const float*)d_in[19];
  const float* b2b = (const float*)d_in[20];
  const float* mw3 = (const float*)d_in[21];
  const float* mb3 = (const float*)d_in[22];
  const float* b3g = (const float*)d_in[23];
  const float* b3b = (const float*)d_in[24];
  const float* mw4 = (const float*)d_in[25];
  const float* mb4 = (const float*)d_in[26];

  float* ws = (float*)d_ws;
  int* wsi = (int*)d_ws;
  float* out = (float*)d_out;

  float* accrep = ws + IDX_ACC;
  int* degi = wsi + IDX_DEGI;
  int* cnt = wsi + IDX_CNT;
  int* fill = wsi + IDX_FILL;
  int* rows = wsi + IDX_ROWS;
  int2* epak = (int2*)(wsi + IDX_EPAK);
  float* h1 = ws + IDX_H1;
  float* h2 = ws + IDX_H2;
  float* emb = ws + IDX_EMB;

  hipMemsetAsync(wsi, 0, ZERO_N * sizeof(int), stream);

  k_gemm1<<<(TRIN + 255) / 256, 256, 0, stream>>>(x, bng, bnb, mw1, accrep);
  k_count<<<(EE + 255) / 256, 256, 0, stream>>>(src, dst, degi, cnt);
  k_scan<<<1, 1024, 0, stream>>>(cnt, rows);
  k_fill<<<(EE + 255) / 256, 256, 0, stream>>>(src, dst, degi, rows, fill, epak);
  k_layer<<<256, 1024, 0, stream>>>(cw0, cb0, nullptr, h1, rows, epak, emb, 0);
  k_layer<<<256, 1024, 0, stream>>>(cw1, cb1, h1, h2, rows, epak, emb, 1);
  k_layer<<<256, 1024, 0, stream>>>(cw2, cb2, h2, nullptr, rows, epak, emb, 2);
  k_mlp<<<1, 1024, 0, stream>>>(accrep, emb, bnhg, bnhb, mb1, b1g, b1b,
                                mw2, mb2, b2g, b2b, mw3, mb3, b3g, b3b,
                                mw4, mb4, out);
}